// Round 8
// baseline (1109.194 us; speedup 1.0000x reference)
//
#include <hip/hip_runtime.h>

#define N 128
#define NITER 60
#define RPS 132                    // partial stride: mult of 4 -> b128-aligned groups
#define COLB (32 * RPS + 16)       // colpart base within a row buffer: +16 shifts bank half
#define GBUF (COLB + 16 * RPS)     // 6352 floats per row

typedef float v2f __attribute__((ext_vector_type(2)));
typedef float v4f __attribute__((ext_vector_type(4)));

// r8 = r1's staggered 2-row schedule at the register budget that fits.
// Evidence: busy-work is ~constant 400 µs-eq across r0-r7; wall = work/busy%.
//  - r1: 2 rows x 64el/thread -> >256 regs -> spill (4.8 GB scratch)   [dead]
//  - r2: same at 1 wave/SIMD -> single-wave serial chain, busy 48%     [dead]
//  - r6: occupancy 2x, phase-locked barriers -> busy still 63%         [dead]
//  - r7: role-split waves -> update density halved, busy 48%           [dead]
// This: 512 thr, 2 rows, 8x4 tile/row/thread. State z+w = 128f + ~60 temps
// < 256-reg cap of (512,2) -> 2 waves/SIMD, no spill. EVERY wave runs a dense
// ~250-cyc update every window; the other row's 16 reduce loads are issued
// BEFORE the update (latency hides under it); 1 barrier/row-iter (r4: 2).
// Update tile + quad-reduce = r6's (absmax 0); schedule = r1's (absmax 0);
// sparsemax tail = r7's (absmax 0). fmed3 clamp kept (r5: min/max +73% issue).
template<int Q, int P>
__device__ __forceinline__ void window_step(
    v2f (&z2)[2][8][2], const v2f (&w2)[2][8][2],
    float (&parts)[2][GBUF], float (&yv)[2][N],
    const float* pbP, int q, int m,
    int tr, int tc, int i0, int j0,
    float xmP, bool doUpd, bool store, bool raw)
{
    const float step = 1.0f / 256.0f;   // 1/(2N), exact power of two

    // (1) issue row-P reduce loads first; no uses until after the update,
    // so their ~latency dies under the dense VALU block below.
    float rt[16];
    #pragma unroll
    for (int k = 0; k < 16; ++k) rt[k] = pbP[k * RPS];

    // (2) dense update of row Q (r6's verified 8x4 tile) + publish
    if (doUpd) {
        float* yq = yv[Q];
        v4f ev = *(const v4f*)&yq[j0];          // 4 cols: banks 4tc..4tc+3 (all 32)
        v2f ec0 = ev.lo, ec1 = ev.hi;
        float rowp[8];
        v2f pc0, pc1;
        #pragma unroll
        for (int r = 0; r < 8; ++r) {
            v2f dr = (v2f)yq[i0 + r];           // 2-addr wave broadcast
            v2f t0 = (z2[Q][r][0] + dr) - ec0;
            v2f t1 = (z2[Q][r][1] + dr) - ec1;
            v2f wv0 = w2[Q][r][0], wv1 = w2[Q][r][1];
            v2f zn0, zn1;
            zn0.x = __builtin_amdgcn_fmed3f(t0.x, -wv0.x, wv0.x);
            zn0.y = __builtin_amdgcn_fmed3f(t0.y, -wv0.y, wv0.y);
            zn1.x = __builtin_amdgcn_fmed3f(t1.x, -wv1.x, wv1.x);
            zn1.y = __builtin_amdgcn_fmed3f(t1.y, -wv1.y, wv1.y);
            z2[Q][r][0] = zn0;
            z2[Q][r][1] = zn1;
            v2f pr = zn0 + zn1;
            rowp[r] = pr.x + pr.y;
            pc0 = (r == 0) ? zn0 : pc0 + zn0;
            pc1 = (r == 0) ? zn1 : pc1 + zn1;
        }
        v4f r0v, r1v, c0v;
        r0v.x = rowp[0]; r0v.y = rowp[1]; r0v.z = rowp[2]; r0v.w = rowp[3];
        r1v.x = rowp[4]; r1v.y = rowp[5]; r1v.z = rowp[6]; r1v.w = rowp[7];
        c0v.x = pc0.x; c0v.y = pc0.y; c0v.z = pc1.x; c0v.w = pc1.y;
        *(v4f*)&parts[Q][tc * RPS + i0]        = r0v;
        *(v4f*)&parts[Q][tc * RPS + i0 + 4]    = r1v;
        *(v4f*)&parts[Q][COLB + tr * RPS + j0] = c0v;
    }

    // (3) finish row-P reduce (r6's verified quad tree: q0|q1 row halves,
    // q2|q3 colpart broadcast-dup -> pair-sum gives 2C, halved exactly)
    float acc = 0.0f;
    #pragma unroll
    for (int k = 0; k < 16; ++k) acc += rt[k];
    float acc2  = acc + __shfl_xor(acc, 1, 64);
    float other = __shfl_xor(acc2, 2, 64);
    if (store && q == 0) {
        float y = (xmP - acc2) + 0.5f * other;   // (x - rowsum) + colsum
        // 2^-8 scaling exact: step*yi - step*yj == step*(yi - yj)
        yv[P][m] = raw ? y : step * y;
    }
}

__global__ __launch_bounds__(512, 2)
void gfusedmax_kernel(const float* __restrict__ x,
                      const float* __restrict__ A,
                      float* __restrict__ out)
{
    const int b0  = blockIdx.x * 2;
    const int tid = threadIdx.x;
    const int tr  = tid >> 5;   // 0..15 -> rows 8tr..8tr+7
    const int tc  = tid & 31;   // 0..31 -> cols 4tc..4tc+3
    const int i0  = tr * 8;
    const int j0  = tc * 4;

    __shared__ __align__(16) float parts[2][GBUF];
    __shared__ __align__(16) float yv[2][N];
    __shared__ float sorted[2][N];
    __shared__ float red[2][8];

    const float step = 1.0f / 256.0f;

    // ---- load w tiles for both rows (8x4 each), init z=0 ----
    v2f w2[2][8][2];
    v2f z2[2][8][2];
    #pragma unroll
    for (int qq = 0; qq < 2; ++qq) {
        const float* Ab = A + (size_t)(b0 + qq) * N * N;
        #pragma unroll
        for (int r = 0; r < 8; ++r) {
            v4f p = *(const v4f*)(Ab + (size_t)(i0 + r) * N + j0);
            w2[qq][r][0] = p.lo; w2[qq][r][1] = p.hi;
            z2[qq][r][0] = (v2f)0.0f; z2[qq][r][1] = (v2f)0.0f;
        }
    }

    // quad-reduce role: lanes (4m..4m+3) produce y[m]
    const int m = tid >> 2;
    const int q = tid & 3;
    const float xm0 = x[(size_t)b0 * N + m];
    const float xm1 = x[(size_t)(b0 + 1) * N + m];
    const float* pb0 = &parts[0][0] + ((q == 0) ? m : (q == 1) ? (16 * RPS + m) : (COLB + m));
    const float* pb1 = &parts[1][0] + ((q == 0) ? m : (q == 1) ? (16 * RPS + m) : (COLB + m));

    // seed y = step*x (iteration-0 partials are zero)
    if (tid < N) {
        yv[0][tid] = step * x[(size_t)b0 * N + tid];
        yv[1][tid] = step * x[(size_t)(b0 + 1) * N + tid];
    }
    __syncthreads();

    for (int t = 0; t <= NITER; ++t) {
        // window A: update row0 #t+1 (t<60); reduce row1 (valid t>0, raw at t==60)
        window_step<0, 1>(z2, w2, parts, yv, pb1, q, m, tr, tc, i0, j0,
                          xm1, t < NITER, t > 0, t == NITER);
        __syncthreads();
        if (t == NITER) break;
        // window B: update row1 #t+1; reduce row0 from winA's publish
        //           (raw at t==59, i.e. after row0's update #60)
        window_step<1, 0>(z2, w2, parts, yv, pb0, q, m, tr, tc, i0, j0,
                          xm0, true, true, t == NITER - 1);
        __syncthreads();
    }
    // both yv[] hold raw final y

    // ---- sparsemax: 2 groups of 256 threads, one row each (r7's tail) ----
    const int grp = tid >> 8;
    const int lt  = tid & 255;
    float* yvg = yv[grp];
    float* sog = sorted[grp];
    float v = 0.0f;
    if (lt < N) {
        v = yvg[lt];
        int rk = 0;
        for (int k = 0; k < N; ++k) {
            float u = yvg[k];
            rk += (u > v) || (u == v && k < lt);
        }
        sog[rk] = v;   // rank is a permutation (ties broken by index)
    }
    __syncthreads();

    float s = 0.0f, csum = 0.0f;
    if (lt < N) {
        s = sog[lt];
        for (int mm = 0; mm < N; ++mm) {       // uniform index -> LDS broadcast
            float u = sog[mm];
            if (mm <= lt) csum += u;           // inclusive prefix at sorted pos
        }
    }
    bool maskb = (lt < N) && (1.0f + (float)(lt + 1) * s > csum);
    float aRed = maskb ? s : 0.0f;
    float bRed = maskb ? 1.0f : 0.0f;
    #pragma unroll
    for (int off = 32; off >= 1; off >>= 1) {
        aRed += __shfl_down(aRed, off, 64);
        bRed += __shfl_down(bRed, off, 64);
    }
    const int wid = lt >> 6;   // 0..3 within group
    if ((lt & 63) == 0) { red[grp][wid * 2] = aRed; red[grp][wid * 2 + 1] = bRed; }
    __syncthreads();
    const float tau = (red[grp][0] + red[grp][2] + red[grp][4] + red[grp][6] - 1.0f)
                    / (red[grp][1] + red[grp][3] + red[grp][5] + red[grp][7]);
    if (lt < N) out[(size_t)(b0 + grp) * N + lt] = fmaxf(v - tau, 0.0f);
}

extern "C" void kernel_launch(void* const* d_in, const int* in_sizes, int n_in,
                              void* d_out, int out_size, void* d_ws, size_t ws_size,
                              hipStream_t stream) {
    const float* x = (const float*)d_in[0];
    const float* A = (const float*)d_in[1];
    float* out = (float*)d_out;
    const int B = in_sizes[0] / N;   // 4096 rows
    gfusedmax_kernel<<<B / 2, 512, 0, stream>>>(x, A, out);
}